// Round 1
// baseline (626.687 us; speedup 1.0000x reference)
//
#include <hip/hip_runtime.h>

#define DIMF 128

typedef __bf16 bf16x8 __attribute__((ext_vector_type(8)));
typedef float f32x4 __attribute__((ext_vector_type(4)));

__device__ __forceinline__ unsigned short f2bf(float f) {
    union { float f; unsigned u; } v; v.f = f;
    unsigned r = v.u + 0x7FFFu + ((v.u >> 16) & 1u);
    return (unsigned short)(r >> 16);
}
__device__ __forceinline__ float bf2f(unsigned short h) {
    union { unsigned u; float f; } v; v.u = ((unsigned)h) << 16; return v.f;
}

// ---------------- counting sort of edges by src ----------------

__global__ __launch_bounds__(256) void k_hist(const int* __restrict__ src, int* __restrict__ cnt, int E) {
    int e = blockIdx.x * 256 + threadIdx.x;
    if (e < E) atomicAdd(&cnt[src[e]], 1);
}

__global__ __launch_bounds__(256) void k_scan1(const int* __restrict__ cnt, int* __restrict__ partials, int n) {
    __shared__ int sh[256];
    int t = threadIdx.x;
    int i = blockIdx.x * 256 + t;
    sh[t] = (i < n) ? cnt[i] : 0;
    __syncthreads();
    for (int d = 128; d > 0; d >>= 1) {
        if (t < d) sh[t] += sh[t + d];
        __syncthreads();
    }
    if (t == 0) partials[blockIdx.x] = sh[0];
}

__global__ __launch_bounds__(512) void k_scan2(int* __restrict__ partials, int nb) {
    // single block, Hillis-Steele inclusive scan -> exclusive, nb <= 512
    __shared__ int sh[512];
    int t = threadIdx.x;
    int v = (t < nb) ? partials[t] : 0;
    sh[t] = v;
    __syncthreads();
    for (int d = 1; d < 512; d <<= 1) {
        int x = (t >= d) ? sh[t - d] : 0;
        __syncthreads();
        sh[t] += x;
        __syncthreads();
    }
    if (t < nb) partials[t] = sh[t] - v;  // exclusive prefix of block sums
}

__global__ __launch_bounds__(256) void k_scan3(const int* __restrict__ cnt, const int* __restrict__ partials,
                                               int* __restrict__ offsets, int* __restrict__ cursor, int n) {
    __shared__ int sh[256];
    int t = threadIdx.x;
    int i = blockIdx.x * 256 + t;
    int v = (i < n) ? cnt[i] : 0;
    sh[t] = v;
    __syncthreads();
    for (int d = 1; d < 256; d <<= 1) {
        int x = (t >= d) ? sh[t - d] : 0;
        __syncthreads();
        sh[t] += x;
        __syncthreads();
    }
    if (i < n) {
        int off = partials[blockIdx.x] + sh[t] - v;
        offsets[i] = off;
        cursor[i] = off;
    }
}

__global__ __launch_bounds__(256) void k_fill(const int* __restrict__ src, int* __restrict__ cursor,
                                              int* __restrict__ order, int E) {
    int e = blockIdx.x * 256 + threadIdx.x;
    if (e < E) {
        int p = atomicAdd(&cursor[src[e]], 1);
        order[p] = e;
    }
}

// per-node gather-mean of edge_attr rows -> concat0[:,128:256) as bf16
__global__ void k_gather(const float* __restrict__ ea, const int* __restrict__ order,
                         const int* __restrict__ offsets, const int* __restrict__ cnt,
                         unsigned short* __restrict__ concat0, int n) {
    int node = blockIdx.x;
    if (node >= n) return;
    int c = cnt[node];
    int base = offsets[node];
    int tid = threadIdx.x;  // 128
    float s = 0.f;
    int j = 0;
    for (; j + 1 < c; j += 2) {
        int e0 = order[base + j];
        int e1 = order[base + j + 1];
        float a0 = ea[(size_t)e0 * DIMF + tid];
        float a1 = ea[(size_t)e1 * DIMF + tid];
        s += a0 + a1;
    }
    if (j < c) {
        int e0 = order[base + j];
        s += ea[(size_t)e0 * DIMF + tid];
    }
    float inv = 1.0f / (float)(c > 1 ? c : 1);
    concat0[(size_t)node * 384 + 128 + tid] = f2bf(s * inv);
}

// x (f32) -> concat0[:,0:128) bf16
__global__ __launch_bounds__(256) void k_xcopy(const float* __restrict__ x, unsigned short* __restrict__ concat0, int n) {
    int idx = blockIdx.x * 256 + threadIdx.x;
    if (idx >= n * 32) return;
    int r = idx >> 5, q = (idx & 31) * 4;
    float4 v = *reinterpret_cast<const float4*>(x + (size_t)r * DIMF + q);
    ushort4 o = { f2bf(v.x), f2bf(v.y), f2bf(v.z), f2bf(v.w) };
    *reinterpret_cast<ushort4*>(concat0 + (size_t)r * 384 + q) = o;
}

// u[batch] gather -> concat0[:,256:384) bf16
__global__ __launch_bounds__(256) void k_ucopy(const float* __restrict__ u, const int* __restrict__ batch,
                                               unsigned short* __restrict__ concat0, int n) {
    int idx = blockIdx.x * 256 + threadIdx.x;
    if (idx >= n * 32) return;
    int r = idx >> 5, q = (idx & 31) * 4;
    int b = batch[r];
    float4 v = *reinterpret_cast<const float4*>(u + (size_t)b * DIMF + q);
    ushort4 o = { f2bf(v.x), f2bf(v.y), f2bf(v.z), f2bf(v.w) };
    *reinterpret_cast<ushort4*>(concat0 + (size_t)r * 384 + 256 + q) = o;
}

__global__ __launch_bounds__(256) void k_wconv(const float* __restrict__ W, unsigned short* __restrict__ Wb, int n4) {
    int idx = blockIdx.x * 256 + threadIdx.x;
    if (idx >= n4) return;
    float4 v = *reinterpret_cast<const float4*>(W + (size_t)idx * 4);
    ushort4 o = { f2bf(v.x), f2bf(v.y), f2bf(v.z), f2bf(v.w) };
    *reinterpret_cast<ushort4*>(Wb + (size_t)idx * 4) = o;
}

// ---------------- bf16 MFMA GEMM: H = relu(A @ W^T + bias), H bf16 ----------------
// A: [rows][K] bf16, W: [128][K] bf16, bias f32[128]
#define BM 64
#define BK 64

__global__ __launch_bounds__(256) void k_gemm(const unsigned short* __restrict__ A,
                                              const unsigned short* __restrict__ W,
                                              const float* __restrict__ bias,
                                              unsigned short* __restrict__ H,
                                              int rows, int K) {
    __shared__ __align__(16) unsigned short lA[BM][BK + 8];
    __shared__ __align__(16) unsigned short lB[DIMF][BK + 8];
    int tid = threadIdx.x;
    int lane = tid & 63, wave = tid >> 6;
    int wm = wave >> 1, wn = wave & 1;  // 2x2 wave grid: 32 rows x 64 cols each
    int l15 = lane & 15, l4 = lane >> 4;
    int row0 = blockIdx.x * BM;

    f32x4 acc[2][4] = {};

    int ar = tid >> 2;            // 0..63
    int ac = (tid & 3) * 16;      // 16 bf16 = 32B per thread
    int br = tid >> 1;            // 0..127
    int bc = (tid & 1) * 32;      // 32 bf16 = 64B per thread

    for (int kt = 0; kt < K; kt += BK) {
        // stage A tile
        {
            int gr = row0 + ar;
            uint4 v0 = {0, 0, 0, 0}, v1 = {0, 0, 0, 0};
            if (gr < rows) {
                const uint4* srcp = reinterpret_cast<const uint4*>(A + (size_t)gr * K + kt + ac);
                v0 = srcp[0];
                v1 = srcp[1];
            }
            *reinterpret_cast<uint4*>(&lA[ar][ac]) = v0;
            *reinterpret_cast<uint4*>(&lA[ar][ac + 8]) = v1;
        }
        // stage B tile (W rows = output features)
        {
            const uint4* srcp = reinterpret_cast<const uint4*>(W + (size_t)br * K + kt + bc);
            uint4 v0 = srcp[0], v1 = srcp[1], v2 = srcp[2], v3 = srcp[3];
            *reinterpret_cast<uint4*>(&lB[br][bc]) = v0;
            *reinterpret_cast<uint4*>(&lB[br][bc + 8]) = v1;
            *reinterpret_cast<uint4*>(&lB[br][bc + 16]) = v2;
            *reinterpret_cast<uint4*>(&lB[br][bc + 24]) = v3;
        }
        __syncthreads();
#pragma unroll
        for (int ks = 0; ks < 2; ++ks) {
            bf16x8 af[2], bfr[4];
#pragma unroll
            for (int mi = 0; mi < 2; ++mi)
                af[mi] = *reinterpret_cast<const bf16x8*>(&lA[wm * 32 + mi * 16 + l15][ks * 32 + l4 * 8]);
#pragma unroll
            for (int ni = 0; ni < 4; ++ni)
                bfr[ni] = *reinterpret_cast<const bf16x8*>(&lB[wn * 64 + ni * 16 + l15][ks * 32 + l4 * 8]);
#pragma unroll
            for (int mi = 0; mi < 2; ++mi)
#pragma unroll
                for (int ni = 0; ni < 4; ++ni)
                    acc[mi][ni] = __builtin_amdgcn_mfma_f32_16x16x32_bf16(af[mi], bfr[ni], acc[mi][ni], 0, 0, 0);
        }
        __syncthreads();
    }

    // epilogue: bias + relu + bf16 store
#pragma unroll
    for (int mi = 0; mi < 2; ++mi) {
#pragma unroll
        for (int i = 0; i < 4; ++i) {
            int r = row0 + wm * 32 + mi * 16 + l4 * 4 + i;
            if (r < rows) {
#pragma unroll
                for (int ni = 0; ni < 4; ++ni) {
                    int c = wn * 64 + ni * 16 + l15;
                    float z = acc[mi][ni][i] + bias[c];
                    z = z > 0.f ? z : 0.f;
                    H[(size_t)r * DIMF + c] = f2bf(z);
                }
            }
        }
    }
}

// per-feature sum & sumsq of bf16 H -> st[0:128)=sum, st[128:256)=sumsq
__global__ __launch_bounds__(256) void k_stats(const unsigned short* __restrict__ H, int rows, float* __restrict__ st) {
    int tid = threadIdx.x;
    int cp = tid & 63;   // column pair
    int rs = tid >> 6;   // 4 row groups
    float s0 = 0.f, q0 = 0.f, s1 = 0.f, q1 = 0.f;
    for (int r = blockIdx.x * 4 + rs; r < rows; r += gridDim.x * 4) {
        unsigned v = *reinterpret_cast<const unsigned*>(H + (size_t)r * DIMF + cp * 2);
        float a = bf2f((unsigned short)(v & 0xFFFFu));
        float b = bf2f((unsigned short)(v >> 16));
        s0 += a; q0 += a * a;
        s1 += b; q1 += b * b;
    }
    __shared__ float buf[4][DIMF];
    buf[rs][cp * 2] = s0; buf[rs][cp * 2 + 1] = s1;
    __syncthreads();
    if (tid < DIMF) {
        float t = buf[0][tid] + buf[1][tid] + buf[2][tid] + buf[3][tid];
        atomicAdd(&st[tid], t);
    }
    __syncthreads();
    buf[rs][cp * 2] = q0; buf[rs][cp * 2 + 1] = q1;
    __syncthreads();
    if (tid < DIMF) {
        float t = buf[0][tid] + buf[1][tid] + buf[2][tid] + buf[3][tid];
        atomicAdd(&st[DIMF + tid], t);
    }
}

// fold BN(prev layer) into next layer weights: W' = W * s[i], b' = b + W @ t
__global__ __launch_bounds__(128) void k_fold(const float* __restrict__ st, const float* __restrict__ g,
                                              const float* __restrict__ bt, const float* __restrict__ Wn,
                                              const float* __restrict__ bn, unsigned short* __restrict__ Wb,
                                              float* __restrict__ bb, int rows) {
    __shared__ float sS[DIMF], sT[DIMF];
    int o = threadIdx.x;
    float invn = 1.0f / (float)rows;
    float mu = st[o] * invn;
    float var = st[DIMF + o] * invn - mu * mu;
    var = var > 0.f ? var : 0.f;
    float rsq = rsqrtf(var + 1e-5f);
    float sc = rsq * g[o];
    sS[o] = sc;
    sT[o] = bt[o] - mu * sc;
    __syncthreads();
    float accv = bn[o];
    for (int i = 0; i < DIMF; ++i) {
        float w = Wn[(size_t)o * DIMF + i];
        Wb[(size_t)o * DIMF + i] = f2bf(w * sS[i]);
        accv += w * sT[i];
    }
    bb[o] = accv;
}

__global__ __launch_bounds__(128) void k_bnprep(const float* __restrict__ st, const float* __restrict__ g,
                                                const float* __restrict__ bt, float* __restrict__ s2t2, int rows) {
    int o = threadIdx.x;
    float invn = 1.0f / (float)rows;
    float mu = st[o] * invn;
    float var = st[DIMF + o] * invn - mu * mu;
    var = var > 0.f ? var : 0.f;
    float rsq = rsqrtf(var + 1e-5f);
    float sc = rsq * g[o];
    s2t2[o] = sc;
    s2t2[DIMF + o] = bt[o] - mu * sc;
}

__global__ __launch_bounds__(256) void k_final(const unsigned short* __restrict__ H, const float* __restrict__ s2t2,
                                               float* __restrict__ out, int n) {
    int idx = blockIdx.x * 256 + threadIdx.x;
    if (idx >= n * 32) return;
    int r = idx >> 5, q = (idx & 31) * 4;
    ushort4 h = *reinterpret_cast<const ushort4*>(H + (size_t)r * DIMF + q);
    float4 o;
    o.x = bf2f(h.x) * s2t2[q + 0] + s2t2[DIMF + q + 0];
    o.y = bf2f(h.y) * s2t2[q + 1] + s2t2[DIMF + q + 1];
    o.z = bf2f(h.z) * s2t2[q + 2] + s2t2[DIMF + q + 2];
    o.w = bf2f(h.w) * s2t2[q + 3] + s2t2[DIMF + q + 3];
    *reinterpret_cast<float4*>(out + (size_t)r * DIMF + q) = o;
}

extern "C" void kernel_launch(void* const* d_in, const int* in_sizes, int n_in,
                              void* d_out, int out_size, void* d_ws, size_t ws_size,
                              hipStream_t stream) {
    const float* x   = (const float*)d_in[0];
    const float* ea  = (const float*)d_in[1];
    const float* u   = (const float*)d_in[2];
    const int* eidx  = (const int*)d_in[3];
    const int* batch = (const int*)d_in[4];
    const float* W0  = (const float*)d_in[5];
    const float* b0  = (const float*)d_in[6];
    const float* W1  = (const float*)d_in[7];
    const float* b1  = (const float*)d_in[8];
    const float* W2  = (const float*)d_in[9];
    const float* b2  = (const float*)d_in[10];
    const float* g0  = (const float*)d_in[11];
    const float* bt0 = (const float*)d_in[12];
    const float* g1  = (const float*)d_in[13];
    const float* bt1 = (const float*)d_in[14];
    const float* g2  = (const float*)d_in[15];
    const float* bt2 = (const float*)d_in[16];

    int N = in_sizes[0] / DIMF;
    int E = in_sizes[1] / DIMF;
    const int* src = eidx;  // row 0 of edge_index

    // workspace layout
    char* base = (char*)d_ws;
    size_t o = 0;
    auto alloc = [&](size_t sz) { size_t p = o; o = (o + sz + 255) & ~(size_t)255; return p; };
    size_t off_cnt      = alloc((size_t)N * 4);
    size_t off_offsets  = alloc((size_t)N * 4);
    size_t off_cursor   = alloc((size_t)N * 4);
    size_t off_order    = alloc((size_t)E * 4);
    size_t off_partials = alloc(512 * 4);
    size_t off_st       = alloc(3 * 256 * 4);
    size_t off_s2t2     = alloc(256 * 4);
    size_t off_W0b      = alloc((size_t)DIMF * 384 * 2);
    size_t off_W1b      = alloc((size_t)DIMF * DIMF * 2);
    size_t off_W2b      = alloc((size_t)DIMF * DIMF * 2);
    size_t off_b1f      = alloc(DIMF * 4);
    size_t off_b2f      = alloc(DIMF * 4);
    size_t off_h0       = alloc((size_t)N * DIMF * 2);
    size_t off_concat0  = alloc((size_t)N * 384 * 2);

    int* cnt        = (int*)(base + off_cnt);
    int* offsets    = (int*)(base + off_offsets);
    int* cursor     = (int*)(base + off_cursor);
    int* order      = (int*)(base + off_order);
    int* partials   = (int*)(base + off_partials);
    float* st       = (float*)(base + off_st);
    float* s2t2     = (float*)(base + off_s2t2);
    unsigned short* W0b = (unsigned short*)(base + off_W0b);
    unsigned short* W1b = (unsigned short*)(base + off_W1b);
    unsigned short* W2b = (unsigned short*)(base + off_W2b);
    float* b1f      = (float*)(base + off_b1f);
    float* b2f      = (float*)(base + off_b2f);
    unsigned short* h0      = (unsigned short*)(base + off_h0);
    unsigned short* concat0 = (unsigned short*)(base + off_concat0);
    unsigned short* h1 = concat0;                               // overlay: concat0 dead after gemm0
    unsigned short* h2 = concat0 + (size_t)N * DIMF;            // second half of concat0 region
    float* outp = (float*)d_out;

    int NB = (N + 255) / 256;
    int EB = (E + 255) / 256;
    int NQ = (N * 32 + 255) / 256;
    int GB = (N + BM - 1) / BM;

    hipMemsetAsync(cnt, 0, (size_t)N * 4, stream);
    hipMemsetAsync(st, 0, 3 * 256 * 4, stream);

    k_hist<<<EB, 256, 0, stream>>>(src, cnt, E);
    k_scan1<<<NB, 256, 0, stream>>>(cnt, partials, N);
    k_scan2<<<1, 512, 0, stream>>>(partials, NB);
    k_scan3<<<NB, 256, 0, stream>>>(cnt, partials, offsets, cursor, N);
    k_fill<<<EB, 256, 0, stream>>>(src, cursor, order, E);
    k_gather<<<N, DIMF, 0, stream>>>(ea, order, offsets, cnt, concat0, N);
    k_xcopy<<<NQ, 256, 0, stream>>>(x, concat0, N);
    k_ucopy<<<NQ, 256, 0, stream>>>(u, batch, concat0, N);
    k_wconv<<<48, 256, 0, stream>>>(W0, W0b, DIMF * 384 / 4);

    // layer 0
    k_gemm<<<GB, 256, 0, stream>>>(concat0, W0b, b0, h0, N, 384);
    k_stats<<<512, 256, 0, stream>>>(h0, N, st);
    k_fold<<<1, 128, 0, stream>>>(st, g0, bt0, W1, b1, W1b, b1f, N);
    // layer 1
    k_gemm<<<GB, 256, 0, stream>>>(h0, W1b, b1f, h1, N, DIMF);
    k_stats<<<512, 256, 0, stream>>>(h1, N, st + 256);
    k_fold<<<1, 128, 0, stream>>>(st + 256, g1, bt1, W2, b2, W2b, b2f, N);
    // layer 2
    k_gemm<<<GB, 256, 0, stream>>>(h1, W2b, b2f, h2, N, DIMF);
    k_stats<<<512, 256, 0, stream>>>(h2, N, st + 512);
    k_bnprep<<<1, 128, 0, stream>>>(st + 512, g2, bt2, s2t2, N);
    k_final<<<NQ, 256, 0, stream>>>(h2, s2t2, outp, N);
}